// Round 2
// baseline (301.996 us; speedup 1.0000x reference)
//
#include <hip/hip_runtime.h>

// DirectionalConv3d: B=8, C_IN=C_OUT=64, T=R=32, CO=32
// v3 design (latency-focused):
//  pass 1 (prep2): x fp32 [b][ch][s] -> bf16 [b][s][ch] in d_ws (+ bf16 weights).
//    LDS-free: thread = 2 output chunks, float2 reads along s, full-line
//    coalescing both directions, 4096 small blocks (latency-immune).
//  pass 2 (conv3): 512-thr / 8-wave blocks (4 s-quarters x 2 o-halves) ->
//    32 waves/CU nominal. All 28 B-fragments preloaded to VGPRs. 5 near taps
//    (self, r+-, c+-) read A from a 40KB xor-swizzled LDS tile staged with
//    contiguous 16B loads (bf16 [s][ch] rows are contiguous); t+-1 taps gather
//    16B frags from global. Per-thread global loads: 49 (was 112).
// Tier 2 fallback: fused LDS kernel reading fp32 x (ws >= 56KB only).
// Tier 3 fallback: fp32 direct.

#define SB 32768   // spatial per batch (T*R*CO)
#define CIN 64
#define COUT 64
#define NB 8

typedef short s16x8 __attribute__((ext_vector_type(8)));
typedef __bf16 bf16x8 __attribute__((ext_vector_type(8)));
typedef float f32x4 __attribute__((ext_vector_type(4)));

__device__ __forceinline__ unsigned f2bf(float f) {
    unsigned u = __float_as_uint(f);
    u += 0x7FFFu + ((u >> 16) & 1u);   // round-to-nearest-even
    return u >> 16;
}
__device__ __forceinline__ unsigned pk2(float lo, float hi) {
    return f2bf(lo) | (f2bf(hi) << 16);
}

// ---------------- weight prep (tier-2 path): fp32 -> bf16, [tap][o][i] ----------------
__global__ __launch_bounds__(256) void wprep_kernel(const float* __restrict__ w0,
                            const float* __restrict__ w1, const float* __restrict__ w2,
                            const float* __restrict__ w3, const float* __restrict__ w4,
                            const float* __restrict__ w5, const float* __restrict__ w6,
                            unsigned short* __restrict__ ws) {
    int tap = blockIdx.x;
    int tid = threadIdx.x;
    const float* w = (tap == 0) ? w0 : (tap == 1) ? w1 : (tap == 2) ? w2
                   : (tap == 3) ? w3 : (tap == 4) ? w4 : (tap == 5) ? w5 : w6;
    unsigned p[8];
#pragma unroll
    for (int j = 0; j < 8; ++j)
        p[j] = pk2(w[tid * 16 + 2 * j], w[tid * 16 + 2 * j + 1]);
    uint4* dp = (uint4*)(ws + tap * 4096 + tid * 16);
    dp[0] = make_uint4(p[0], p[1], p[2], p[3]);
    dp[1] = make_uint4(p[4], p[5], p[6], p[7]);
}

// ---------------- pass 1: weights + x transpose/convert (LDS-free) ----------------
// grid 4103 = 4096 x-blocks + 7 weight taps. x-block: 256 thr, thread owns
// (b, s2, cg) producing rows s=2*s2, s+1 chunk cg (8 channels):
//   reads 8 x float2 along s (8 lanes/channel-group cover a full 64B line),
//   writes 2 x uint4 (128B-contiguous per 8 lanes).
// XCD chunking: batch b -> XCD b, so xq[b] lands hot in XCD b's L2 for conv3.
__global__ __launch_bounds__(256) void prep2_kernel(const float* __restrict__ x,
                            const float* __restrict__ w0, const float* __restrict__ w1,
                            const float* __restrict__ w2, const float* __restrict__ w3,
                            const float* __restrict__ w4, const float* __restrict__ w5,
                            const float* __restrict__ w6,
                            unsigned short* __restrict__ ws) {
    int bid = blockIdx.x;
    int tid = threadIdx.x;
    if (bid >= 4096) {                 // weight blocks
        int tap = bid - 4096;
        const float* w = (tap == 0) ? w0 : (tap == 1) ? w1 : (tap == 2) ? w2
                       : (tap == 3) ? w3 : (tap == 4) ? w4 : (tap == 5) ? w5 : w6;
        unsigned p[8];
#pragma unroll
        for (int j = 0; j < 8; ++j)
            p[j] = pk2(w[tid * 16 + 2 * j], w[tid * 16 + 2 * j + 1]);
        uint4* dp = (uint4*)(ws + tap * 4096 + tid * 16);
        dp[0] = make_uint4(p[0], p[1], p[2], p[3]);
        dp[1] = make_uint4(p[4], p[5], p[6], p[7]);
        return;
    }
    int lbid = ((bid & 7) << 9) | (bid >> 3);   // bijective: 4096 % 8 == 0
    int b = lbid >> 9;                          // batch = XCD
    int i = (lbid & 511) * 256 + tid;           // [0, 131072) per batch
    int cg = i & 7;                             // channel group (8 ch)
    int s = (i >> 3) * 2;                       // even spatial row
    const float* xb = x + (size_t)b * CIN * SB;
    unsigned short* xq = ws + 7 * 4096;
    unsigned pa[4], pb[4];
#pragma unroll
    for (int u = 0; u < 4; ++u) {
        int ch = cg * 8 + 2 * u;
        float2 v0 = *(const float2*)(xb + (size_t)ch * SB + s);
        float2 v1 = *(const float2*)(xb + (size_t)(ch + 1) * SB + s);
        pa[u] = pk2(v0.x, v1.x);
        pb[u] = pk2(v0.y, v1.y);
    }
    uint4* dst = (uint4*)(xq + ((size_t)b * SB + s) * 64 + cg * 8);
    dst[0] = make_uint4(pa[0], pa[1], pa[2], pa[3]);   // row s
    dst[8] = make_uint4(pb[0], pb[1], pb[2], pb[3]);   // row s+1 (+128B)
}

// ---------------- pass 2: 8-wave MFMA conv ----------------
// grid 1024 = 8 b x 128 s-tiles of 256 (XCD-chunked: batch b pinned to XCD b).
// Block 512 thr = 8 waves: wave (sq, oh) = 64 s x 32 o, acc[4][2],
// K=448 via mfma_f32_16x16x32_bf16.
__global__ __launch_bounds__(512, 8) void conv3_kernel(const unsigned short* __restrict__ xq,
                                                       const unsigned short* __restrict__ wq,
                                                       float* __restrict__ out) {
    __shared__ uint4 alds[2560];   // 40 KB: rows sblk-32 .. sblk+288, 16B-chunk xor swizzle
    int bid = blockIdx.x;
    int lbid = ((bid & 7) << 7) | (bid >> 3);   // bijective: 1024 % 8 == 0
    int b = lbid >> 7;
    int sblk = (lbid & 127) << 8;
    int tid = threadIdx.x;
    int lane = tid & 63;
    int wv = tid >> 6;                           // 0..7
    int lo = lane & 15;
    int quad = lane >> 4;
    int oh = wv & 1;                             // o-half
    int sq = wv >> 1;                            // s-quarter
    int sbase = sblk + sq * 64;
    int t = sblk >> 10;                          // uniform within block
    const unsigned short* xb = xq + (size_t)b * (CIN * SB);

    // ---- B preload: all 28 fragments into VGPRs (static indices only) ----
    bf16x8 bq[7][2][2];
#pragma unroll
    for (int tap = 0; tap < 7; ++tap)
#pragma unroll
        for (int ks = 0; ks < 2; ++ks)
#pragma unroll
            for (int nt = 0; nt < 2; ++nt) {
                const unsigned short* bp = wq + tap * 4096
                    + (oh * 32 + nt * 16 + lo) * 64 + ks * 32 + quad * 8;
                bq[tap][ks][nt] = __builtin_bit_cast(bf16x8, *(const s16x8*)bp);
            }

    // ---- stage 40KB tile: contiguous rows of xq, xor-swizzled into LDS ----
    {
        const uint4* src = (const uint4*)xb;     // chunk index = row*8 + col
#pragma unroll
        for (int u = 0; u < 5; ++u) {
            int idx = u * 512 + tid;             // 0..2559
            int row = idx >> 3;                  // local row (0..319)
            int col = idx & 7;
            int gr = sblk - 32 + row;
            gr = gr < 0 ? 0 : (gr > SB - 1 ? SB - 1 : gr);  // clamped rows feed masked lanes only
            uint4 v = src[gr * 8 + col];
            alds[row * 8 + (col ^ (row & 7))] = v;
        }
    }
    __syncthreads();

    f32x4 acc[4][2];
#pragma unroll
    for (int mt = 0; mt < 4; ++mt)
#pragma unroll
        for (int nt = 0; nt < 2; ++nt)
            acc[mt][nt] = (f32x4){0.f, 0.f, 0.f, 0.f};

    int s_m[4], r_m[4], c_m[4], rl[4];
#pragma unroll
    for (int mt = 0; mt < 4; ++mt) {
        int s = sbase + mt * 16 + lo;            // A row: m = lane&15
        s_m[mt] = s;
        r_m[mt] = (s >> 5) & 31;
        c_m[mt] = s & 31;
        rl[mt] = s - sblk + 32;                  // LDS local row
    }

    const s16x8 zz = {0, 0, 0, 0, 0, 0, 0, 0};

    // near taps (self, r+-, c+-): A from swizzled LDS, per-lane mask
    auto run_tap_lds = [&](const bf16x8 (&bt)[2][2], int d, const bool (&ok)[4]) {
#pragma unroll
        for (int ks = 0; ks < 2; ++ks) {
#pragma unroll
            for (int mt = 0; mt < 4; ++mt) {
                int row = rl[mt] + d;            // always in [0,320)
                s16x8 raw = *((const s16x8*)alds + row * 8 + ((ks * 4 + quad) ^ (row & 7)));
                raw = ok[mt] ? raw : zz;
                bf16x8 af = __builtin_bit_cast(bf16x8, raw);
                acc[mt][0] = __builtin_amdgcn_mfma_f32_16x16x32_bf16(af, bt[ks][0], acc[mt][0], 0, 0, 0);
                acc[mt][1] = __builtin_amdgcn_mfma_f32_16x16x32_bf16(af, bt[ks][1], acc[mt][1], 0, 0, 0);
            }
        }
    };

    // t+-1 taps: block-uniform validity, contiguous 16B gathers from xq
    auto run_tap_gather = [&](const bf16x8 (&bt)[2][2], int d) {
#pragma unroll
        for (int ks = 0; ks < 2; ++ks) {
#pragma unroll
            for (int mt = 0; mt < 4; ++mt) {
                s16x8 raw = *(const s16x8*)(xb + (size_t)(s_m[mt] + d) * 64 + ks * 32 + quad * 8);
                bf16x8 af = __builtin_bit_cast(bf16x8, raw);
                acc[mt][0] = __builtin_amdgcn_mfma_f32_16x16x32_bf16(af, bt[ks][0], acc[mt][0], 0, 0, 0);
                acc[mt][1] = __builtin_amdgcn_mfma_f32_16x16x32_bf16(af, bt[ks][1], acc[mt][1], 0, 0, 0);
            }
        }
    };

    {
        bool ok_all[4] = {true, true, true, true};
        run_tap_lds(bq[0], 0, ok_all);           // self
    }
    if (t > 0)  run_tap_gather(bq[1], -1024);    // t-1
    if (t < 31) run_tap_gather(bq[2], 1024);     // t+1
    {
        bool ok[4];
#pragma unroll
        for (int mt = 0; mt < 4; ++mt) ok[mt] = (r_m[mt] > 0);
        run_tap_lds(bq[3], -32, ok);             // r-1
#pragma unroll
        for (int mt = 0; mt < 4; ++mt) ok[mt] = (r_m[mt] < 31);
        run_tap_lds(bq[4], 32, ok);              // r+1
#pragma unroll
        for (int mt = 0; mt < 4; ++mt) ok[mt] = (c_m[mt] > 0);
        run_tap_lds(bq[5], -1, ok);              // c-1
#pragma unroll
        for (int mt = 0; mt < 4; ++mt) ok[mt] = (c_m[mt] < 31);
        run_tap_lds(bq[6], 1, ok);               // c+1
    }

    // D layout: col(n=o) = lane&15, row(m=s) = quad*4 + reg -> full 64B lines per wave
#pragma unroll
    for (int mt = 0; mt < 4; ++mt) {
#pragma unroll
        for (int nt = 0; nt < 2; ++nt) {
            int o = oh * 32 + nt * 16 + lo;
            size_t off = ((size_t)(b * COUT + o)) * SB + sbase + mt * 16 + quad * 4;
            *(f32x4*)(out + off) = acc[mt][nt];
        }
    }
}

// ---------------- tier-2 fallback: fused LDS kernel on fp32 x ----------------
__global__ __launch_bounds__(256) void conv_kernel(const float* __restrict__ x,
                                                   const unsigned short* __restrict__ wq,
                                                   float* __restrict__ out) {
    __shared__ uint4 alds[2560];
    int bid = blockIdx.x;
    int b = bid >> 7;
    int sblk = (bid & 127) << 8;
    int tid = threadIdx.x;
    const float* xb = x + (size_t)b * CIN * SB;

    {
        int rl = 32 + tid;
        const float* xp = xb + sblk + tid;
#pragma unroll
        for (int c = 0; c < 4; ++c) {
            unsigned pk[8];
#pragma unroll
            for (int u = 0; u < 8; ++u)
                pk[u] = pk2(xp[(size_t)(c * 16 + 2 * u) * SB],
                            xp[(size_t)(c * 16 + 2 * u + 1) * SB]);
            alds[rl * 8 + ((2 * c) ^ (rl & 7))] = make_uint4(pk[0], pk[1], pk[2], pk[3]);
            alds[rl * 8 + ((2 * c + 1) ^ (rl & 7))] = make_uint4(pk[4], pk[5], pk[6], pk[7]);
        }
    }
    {
        int hrow = tid & 63;
        int rl = (hrow < 32) ? hrow : hrow + 256;
        int s = sblk - 32 + rl;
        s = max(0, min(SB - 1, s));
        int ic = tid >> 6;
        const float* xp = xb + s + (size_t)(ic * 16) * SB;
        unsigned pk[8];
#pragma unroll
        for (int u = 0; u < 8; ++u)
            pk[u] = pk2(xp[(size_t)(2 * u) * SB], xp[(size_t)(2 * u + 1) * SB]);
        alds[rl * 8 + ((2 * ic) ^ (rl & 7))] = make_uint4(pk[0], pk[1], pk[2], pk[3]);
        alds[rl * 8 + ((2 * ic + 1) ^ (rl & 7))] = make_uint4(pk[4], pk[5], pk[6], pk[7]);
    }
    __syncthreads();

    int lane = tid & 63;
    int wv = tid >> 6;
    int lo = lane & 15;
    int quad = lane >> 4;
    int sbase = sblk + wv * 64;
    int t = sblk >> 10;

    f32x4 acc[4][4];
#pragma unroll
    for (int mt = 0; mt < 4; ++mt)
#pragma unroll
        for (int nt = 0; nt < 4; ++nt)
            acc[mt][nt] = (f32x4){0.f, 0.f, 0.f, 0.f};

    int r_m[4], c_m[4], rl[4];
#pragma unroll
    for (int mt = 0; mt < 4; ++mt) {
        int s = sbase + mt * 16 + lo;
        r_m[mt] = (s >> 5) & 31;
        c_m[mt] = s & 31;
        rl[mt] = s - sblk + 32;
    }

    auto load_b = [&](const unsigned short* wt, int ks, int nt) -> bf16x8 {
        const unsigned short* bp = wt + (nt * 16 + lo) * 64 + ks * 32 + quad * 8;
        return __builtin_bit_cast(bf16x8, *(const s16x8*)bp);
    };

    auto run_tap_lds = [&](int tap, int d, const bool ok[4]) {
        const unsigned short* wt = wq + tap * 4096;
#pragma unroll
        for (int ks = 0; ks < 2; ++ks) {
            bf16x8 bf[4];
#pragma unroll
            for (int nt = 0; nt < 4; ++nt) bf[nt] = load_b(wt, ks, nt);
            int j = ks * 4 + quad;
#pragma unroll
            for (int mt = 0; mt < 4; ++mt) {
                int row = rl[mt] + d;
                s16x8 raw = *((const s16x8*)alds + row * 8 + (j ^ (row & 7)));
                s16x8 zx = {0, 0, 0, 0, 0, 0, 0, 0};
                raw = ok[mt] ? raw : zx;
                bf16x8 af = __builtin_bit_cast(bf16x8, raw);
#pragma unroll
                for (int nt = 0; nt < 4; ++nt)
                    acc[mt][nt] = __builtin_amdgcn_mfma_f32_16x16x32_bf16(af, bf[nt], acc[mt][nt], 0, 0, 0);
            }
        }
    };

    auto run_tap_gather = [&](int tap, int d) {
        const unsigned short* wt = wq + tap * 4096;
#pragma unroll
        for (int ks = 0; ks < 2; ++ks) {
            bf16x8 bf[4];
#pragma unroll
            for (int nt = 0; nt < 4; ++nt) bf[nt] = load_b(wt, ks, nt);
            const float* gp = xb + (size_t)(ks * 32 + quad * 8) * SB + d;
#pragma unroll
            for (int mt = 0; mt < 4; ++mt) {
                const float* ap = gp + sbase + mt * 16 + lo;
                unsigned pk[4];
#pragma unroll
                for (int u = 0; u < 4; ++u)
                    pk[u] = pk2(ap[(size_t)(2 * u) * SB], ap[(size_t)(2 * u + 1) * SB]);
                uint4 v = make_uint4(pk[0], pk[1], pk[2], pk[3]);
                bf16x8 af = __builtin_bit_cast(bf16x8, v);
#pragma unroll
                for (int nt = 0; nt < 4; ++nt)
                    acc[mt][nt] = __builtin_amdgcn_mfma_f32_16x16x32_bf16(af, bf[nt], acc[mt][nt], 0, 0, 0);
            }
        }
    };

    {
        bool ok_all[4] = {true, true, true, true};
        run_tap_lds(0, 0, ok_all);
    }
    if (t > 0)  run_tap_gather(1, -1024);
    if (t < 31) run_tap_gather(2, 1024);
    {
        bool ok[4];
#pragma unroll
        for (int mt = 0; mt < 4; ++mt) ok[mt] = (r_m[mt] > 0);
        run_tap_lds(3, -32, ok);
#pragma unroll
        for (int mt = 0; mt < 4; ++mt) ok[mt] = (r_m[mt] < 31);
        run_tap_lds(4, 32, ok);
#pragma unroll
        for (int mt = 0; mt < 4; ++mt) ok[mt] = (c_m[mt] > 0);
        run_tap_lds(5, -1, ok);
#pragma unroll
        for (int mt = 0; mt < 4; ++mt) ok[mt] = (c_m[mt] < 31);
        run_tap_lds(6, 1, ok);
    }

#pragma unroll
    for (int mt = 0; mt < 4; ++mt) {
#pragma unroll
        for (int nt = 0; nt < 4; ++nt) {
            int o = nt * 16 + lo;
            size_t off = ((size_t)(b * COUT + o)) * SB + sbase + mt * 16 + quad * 4;
            *(f32x4*)(out + off) = acc[mt][nt];
        }
    }
}

// ---------------- tier-3 fallback: fp32 direct ----------------
__global__ void fallback_kernel(const float* __restrict__ x,
                                const float* __restrict__ w0, const float* __restrict__ w1,
                                const float* __restrict__ w2, const float* __restrict__ w3,
                                const float* __restrict__ w4, const float* __restrict__ w5,
                                const float* __restrict__ w6,
                                float* __restrict__ out) {
    int bid = blockIdx.x;
    int b = bid >> 11;
    int og = (bid >> 7) & 15;
    int sblk = (bid & 127) << 8;
    int tid = threadIdx.x;
    __shared__ float wl[7][4][64];
    const float* wp[7] = {w0, w1, w2, w3, w4, w5, w6};
    for (int k = tid; k < 7 * 4 * 64; k += 256) {
        int tap = k >> 8, oo = (k >> 6) & 3, i = k & 63;
        wl[tap][oo][i] = wp[tap][(og * 4 + oo) * 64 + i];
    }
    __syncthreads();
    int s = sblk + tid;
    int t = s >> 10, r = (s >> 5) & 31, c = s & 31;
    const float* xb = x + (size_t)b * CIN * SB + s;
    float a0 = 0, a1 = 0, a2 = 0, a3 = 0;
    for (int i = 0; i < 64; ++i) {
        const float* xi = xb + (size_t)i * SB;
        float vs = xi[0];
        float vtp = (t > 0) ? xi[-1024] : 0.f;
        float vtm = (t < 31) ? xi[1024] : 0.f;
        float vrp = (r > 0) ? xi[-32] : 0.f;
        float vrm = (r < 31) ? xi[32] : 0.f;
        float vcp = (c > 0) ? xi[-1] : 0.f;
        float vcm = (c < 31) ? xi[1] : 0.f;
        a0 += wl[0][0][i] * vs + wl[1][0][i] * vtp + wl[2][0][i] * vtm + wl[3][0][i] * vrp + wl[4][0][i] * vrm + wl[5][0][i] * vcp + wl[6][0][i] * vcm;
        a1 += wl[0][1][i] * vs + wl[1][1][i] * vtp + wl[2][1][i] * vtm + wl[3][1][i] * vrp + wl[4][1][i] * vrm + wl[5][1][i] * vcp + wl[6][1][i] * vcm;
        a2 += wl[0][2][i] * vs + wl[1][2][i] * vtp + wl[2][2][i] * vtm + wl[3][2][i] * vrp + wl[4][2][i] * vrm + wl[5][2][i] * vcp + wl[6][2][i] * vcm;
        a3 += wl[0][3][i] * vs + wl[1][3][i] * vtp + wl[2][3][i] * vtm + wl[3][3][i] * vrp + wl[4][3][i] * vrm + wl[5][3][i] * vcp + wl[6][3][i] * vcm;
    }
    size_t obase = ((size_t)b * COUT + og * 4) * SB + s;
    out[obase] = a0;
    out[obase + SB] = a1;
    out[obase + 2 * (size_t)SB] = a2;
    out[obase + 3 * (size_t)SB] = a3;
}

extern "C" void kernel_launch(void* const* d_in, const int* in_sizes, int n_in,
                              void* d_out, int out_size, void* d_ws, size_t ws_size,
                              hipStream_t stream) {
    const float* x = (const float*)d_in[0];
    const float* w0 = (const float*)d_in[1];
    const float* w1 = (const float*)d_in[2];
    const float* w2 = (const float*)d_in[3];
    const float* w3 = (const float*)d_in[4];
    const float* w4 = (const float*)d_in[5];
    const float* w5 = (const float*)d_in[6];
    const float* w6 = (const float*)d_in[7];
    float* out = (float*)d_out;

    size_t need_w = (size_t)7 * 4096 * 2;                        // 56 KB weights
    size_t need_full = need_w + (size_t)NB * CIN * SB * 2;       // + 32 MB bf16 x
    if (d_ws != nullptr && ws_size >= need_full) {
        unsigned short* wsp = (unsigned short*)d_ws;
        prep2_kernel<<<4103, 256, 0, stream>>>(x, w0, w1, w2, w3, w4, w5, w6, wsp);
        conv3_kernel<<<1024, 512, 0, stream>>>(wsp + 7 * 4096, wsp, out);
    } else if (d_ws != nullptr && ws_size >= need_w) {
        unsigned short* wsp = (unsigned short*)d_ws;
        wprep_kernel<<<7, 256, 0, stream>>>(w0, w1, w2, w3, w4, w5, w6, wsp);
        conv_kernel<<<1024, 256, 0, stream>>>(x, wsp, out);
    } else {
        fallback_kernel<<<8 * 16 * 128, 256, 0, stream>>>(x, w0, w1, w2, w3, w4, w5, w6, out);
    }
}

// Round 3
// 208.157 us; speedup vs baseline: 1.4508x; 1.4508x over previous
//
#include <hip/hip_runtime.h>

// DirectionalConv3d: B=8, C_IN=C_OUT=64, T=R=32, CO=32
// v4 design:
//  pass 1 (prep2): x fp32 [b][ch][s] -> bf16 [b][s][ch] in d_ws (+ bf16 weights).
//  pass 2 (conv4): latency-focused re-test of round-2 theory WITHOUT the
//    register cap that sank conv3 (no min-waves launch_bounds -> no spill).
//    grid 2048 (8b x 256 s-tiles of 128), 256 thr = 4 waves; wave = 32 s x 64 o
//    (acc[2][4]); 8192 waves total = 8 waves/SIMD nominal (2x conv2).
//    No LDS, no barrier. A-frags: contiguous 16B gathers from bf16 [s][ch];
//    B-frags: 8 per tap loaded once, reused across both mt (L1-hot).
// Tier 2 fallback: fused LDS kernel reading fp32 x (ws >= 56KB only).
// Tier 3 fallback: fp32 direct.

#define SB 32768   // spatial per batch (T*R*CO)
#define CIN 64
#define COUT 64
#define NB 8

typedef short s16x8 __attribute__((ext_vector_type(8)));
typedef __bf16 bf16x8 __attribute__((ext_vector_type(8)));
typedef float f32x4 __attribute__((ext_vector_type(4)));

__device__ __forceinline__ unsigned f2bf(float f) {
    unsigned u = __float_as_uint(f);
    u += 0x7FFFu + ((u >> 16) & 1u);   // round-to-nearest-even
    return u >> 16;
}
__device__ __forceinline__ unsigned pk2(float lo, float hi) {
    return f2bf(lo) | (f2bf(hi) << 16);
}

// ---------------- weight prep (tier-2 path): fp32 -> bf16, [tap][o][i] ----------------
__global__ __launch_bounds__(256) void wprep_kernel(const float* __restrict__ w0,
                            const float* __restrict__ w1, const float* __restrict__ w2,
                            const float* __restrict__ w3, const float* __restrict__ w4,
                            const float* __restrict__ w5, const float* __restrict__ w6,
                            unsigned short* __restrict__ ws) {
    int tap = blockIdx.x;
    int tid = threadIdx.x;
    const float* w = (tap == 0) ? w0 : (tap == 1) ? w1 : (tap == 2) ? w2
                   : (tap == 3) ? w3 : (tap == 4) ? w4 : (tap == 5) ? w5 : w6;
    unsigned p[8];
#pragma unroll
    for (int j = 0; j < 8; ++j)
        p[j] = pk2(w[tid * 16 + 2 * j], w[tid * 16 + 2 * j + 1]);
    uint4* dp = (uint4*)(ws + tap * 4096 + tid * 16);
    dp[0] = make_uint4(p[0], p[1], p[2], p[3]);
    dp[1] = make_uint4(p[4], p[5], p[6], p[7]);
}

// ---------------- pass 1: weights + x transpose/convert (LDS-free) ----------------
// grid 4103 = 4096 x-blocks + 7 weight taps. x-block: 256 thr, thread owns
// (b, s2, cg) producing rows s=2*s2, s+1 chunk cg (8 channels):
//   reads 8 x float2 along s (8 lanes/channel-group cover a full 64B line),
//   writes 2 x uint4 (128B-contiguous per 8 lanes).
// XCD chunking: batch b -> XCD b, so xq[b] lands hot in XCD b's L2 for conv4.
__global__ __launch_bounds__(256) void prep2_kernel(const float* __restrict__ x,
                            const float* __restrict__ w0, const float* __restrict__ w1,
                            const float* __restrict__ w2, const float* __restrict__ w3,
                            const float* __restrict__ w4, const float* __restrict__ w5,
                            const float* __restrict__ w6,
                            unsigned short* __restrict__ ws) {
    int bid = blockIdx.x;
    int tid = threadIdx.x;
    if (bid >= 4096) {                 // weight blocks
        int tap = bid - 4096;
        const float* w = (tap == 0) ? w0 : (tap == 1) ? w1 : (tap == 2) ? w2
                       : (tap == 3) ? w3 : (tap == 4) ? w4 : (tap == 5) ? w5 : w6;
        unsigned p[8];
#pragma unroll
        for (int j = 0; j < 8; ++j)
            p[j] = pk2(w[tid * 16 + 2 * j], w[tid * 16 + 2 * j + 1]);
        uint4* dp = (uint4*)(ws + tap * 4096 + tid * 16);
        dp[0] = make_uint4(p[0], p[1], p[2], p[3]);
        dp[1] = make_uint4(p[4], p[5], p[6], p[7]);
        return;
    }
    int lbid = ((bid & 7) << 9) | (bid >> 3);   // bijective: 4096 % 8 == 0
    int b = lbid >> 9;                          // batch = XCD
    int i = (lbid & 511) * 256 + tid;           // [0, 131072) per batch
    int cg = i & 7;                             // channel group (8 ch)
    int s = (i >> 3) * 2;                       // even spatial row
    const float* xb = x + (size_t)b * CIN * SB;
    unsigned short* xq = ws + 7 * 4096;
    unsigned pa[4], pb[4];
#pragma unroll
    for (int u = 0; u < 4; ++u) {
        int ch = cg * 8 + 2 * u;
        float2 v0 = *(const float2*)(xb + (size_t)ch * SB + s);
        float2 v1 = *(const float2*)(xb + (size_t)(ch + 1) * SB + s);
        pa[u] = pk2(v0.x, v1.x);
        pb[u] = pk2(v0.y, v1.y);
    }
    uint4* dst = (uint4*)(xq + ((size_t)b * SB + s) * 64 + cg * 8);
    dst[0] = make_uint4(pa[0], pa[1], pa[2], pa[3]);   // row s
    dst[8] = make_uint4(pb[0], pb[1], pb[2], pb[3]);   // row s+1 (+128B)
}

// ---------------- pass 2: high-occupancy gather conv ----------------
// grid 2048 = 8 b x 256 s-tiles of 128 (XCD-chunked: batch b pinned to XCD b).
// Block 256 thr = 4 waves; wave: 32 s x 64 o = acc[2][4], K=448 via
// mfma_f32_16x16x32_bf16. 8192 waves = 8 waves/SIMD nominal.
__global__ __launch_bounds__(256) void conv4_kernel(const unsigned short* __restrict__ xq,
                                                    const unsigned short* __restrict__ wq,
                                                    float* __restrict__ out) {
    int bid = blockIdx.x;
    int lbid = ((bid & 7) << 8) | (bid >> 3);   // bijective: 2048 % 8 == 0
    int b = lbid >> 8;
    int sblk = (lbid & 255) << 7;               // 128 rows per block
    int tid = threadIdx.x;
    int lane = tid & 63;
    int wv = tid >> 6;                          // 0..3
    int lo = lane & 15;
    int quad = lane >> 4;
    int sbase = sblk + wv * 32;
    int t = sblk >> 10;                         // uniform within block (128 | 1024)
    const unsigned short* xb = xq + (size_t)b * (CIN * SB);

    f32x4 acc[2][4];
#pragma unroll
    for (int mt = 0; mt < 2; ++mt)
#pragma unroll
        for (int nt = 0; nt < 4; ++nt)
            acc[mt][nt] = (f32x4){0.f, 0.f, 0.f, 0.f};

    int s_m[2], r_m[2], c_m[2];
#pragma unroll
    for (int mt = 0; mt < 2; ++mt) {
        int s = sbase + mt * 16 + lo;           // A row: m = lane&15
        s_m[mt] = s;
        r_m[mt] = (s >> 5) & 31;
        c_m[mt] = s & 31;
    }

    const s16x8 zz = {0, 0, 0, 0, 0, 0, 0, 0};

    // one tap: load its 8 B-frags once (L1-hot), gather A per (ks, mt)
    auto run_tap = [&](int tap, int d, const bool (&ok)[2]) {
        const unsigned short* wt = wq + tap * 4096;
        bf16x8 bf[2][4];
#pragma unroll
        for (int ks = 0; ks < 2; ++ks)
#pragma unroll
            for (int nt = 0; nt < 4; ++nt) {
                const unsigned short* bp = wt + (nt * 16 + lo) * 64 + ks * 32 + quad * 8;
                bf[ks][nt] = __builtin_bit_cast(bf16x8, *(const s16x8*)bp);
            }
#pragma unroll
        for (int ks = 0; ks < 2; ++ks) {
#pragma unroll
            for (int mt = 0; mt < 2; ++mt) {
                int s = s_m[mt] + d;
                s = s < 0 ? 0 : s;              // clamped rows feed masked lanes only
                s = s > SB - 1 ? SB - 1 : s;
                s16x8 raw = *(const s16x8*)(xb + (size_t)s * 64 + ks * 32 + quad * 8);
                raw = ok[mt] ? raw : zz;
                bf16x8 af = __builtin_bit_cast(bf16x8, raw);
#pragma unroll
                for (int nt = 0; nt < 4; ++nt)
                    acc[mt][nt] = __builtin_amdgcn_mfma_f32_16x16x32_bf16(af, bf[ks][nt], acc[mt][nt], 0, 0, 0);
            }
        }
    };

    {
        bool ok_all[2] = {true, true};
        run_tap(0, 0, ok_all);                  // self
        if (t > 0)  run_tap(1, -1024, ok_all);  // t-1 (block-uniform)
        if (t < 31) run_tap(2, 1024, ok_all);   // t+1
    }
    {
        bool ok[2];
#pragma unroll
        for (int mt = 0; mt < 2; ++mt) ok[mt] = (r_m[mt] > 0);
        run_tap(3, -32, ok);                    // r-1
#pragma unroll
        for (int mt = 0; mt < 2; ++mt) ok[mt] = (r_m[mt] < 31);
        run_tap(4, 32, ok);                     // r+1
#pragma unroll
        for (int mt = 0; mt < 2; ++mt) ok[mt] = (c_m[mt] > 0);
        run_tap(5, -1, ok);                     // c-1
#pragma unroll
        for (int mt = 0; mt < 2; ++mt) ok[mt] = (c_m[mt] < 31);
        run_tap(6, 1, ok);                      // c+1
    }

    // D layout: col(n=o) = lane&15, row(m=s) = quad*4 + reg -> full 64B lines per wave
#pragma unroll
    for (int mt = 0; mt < 2; ++mt) {
#pragma unroll
        for (int nt = 0; nt < 4; ++nt) {
            int o = nt * 16 + lo;
            size_t off = ((size_t)(b * COUT + o)) * SB + sbase + mt * 16 + quad * 4;
            *(f32x4*)(out + off) = acc[mt][nt];
        }
    }
}

// ---------------- tier-2 fallback: fused LDS kernel on fp32 x ----------------
__global__ __launch_bounds__(256) void conv_kernel(const float* __restrict__ x,
                                                   const unsigned short* __restrict__ wq,
                                                   float* __restrict__ out) {
    __shared__ uint4 alds[2560];
    int bid = blockIdx.x;
    int b = bid >> 7;
    int sblk = (bid & 127) << 8;
    int tid = threadIdx.x;
    const float* xb = x + (size_t)b * CIN * SB;

    {
        int rl = 32 + tid;
        const float* xp = xb + sblk + tid;
#pragma unroll
        for (int c = 0; c < 4; ++c) {
            unsigned pk[8];
#pragma unroll
            for (int u = 0; u < 8; ++u)
                pk[u] = pk2(xp[(size_t)(c * 16 + 2 * u) * SB],
                            xp[(size_t)(c * 16 + 2 * u + 1) * SB]);
            alds[rl * 8 + ((2 * c) ^ (rl & 7))] = make_uint4(pk[0], pk[1], pk[2], pk[3]);
            alds[rl * 8 + ((2 * c + 1) ^ (rl & 7))] = make_uint4(pk[4], pk[5], pk[6], pk[7]);
        }
    }
    {
        int hrow = tid & 63;
        int rl = (hrow < 32) ? hrow : hrow + 256;
        int s = sblk - 32 + rl;
        s = max(0, min(SB - 1, s));
        int ic = tid >> 6;
        const float* xp = xb + s + (size_t)(ic * 16) * SB;
        unsigned pk[8];
#pragma unroll
        for (int u = 0; u < 8; ++u)
            pk[u] = pk2(xp[(size_t)(2 * u) * SB], xp[(size_t)(2 * u + 1) * SB]);
        alds[rl * 8 + ((2 * ic) ^ (rl & 7))] = make_uint4(pk[0], pk[1], pk[2], pk[3]);
        alds[rl * 8 + ((2 * ic + 1) ^ (rl & 7))] = make_uint4(pk[4], pk[5], pk[6], pk[7]);
    }
    __syncthreads();

    int lane = tid & 63;
    int wv = tid >> 6;
    int lo = lane & 15;
    int quad = lane >> 4;
    int sbase = sblk + wv * 64;
    int t = sblk >> 10;

    f32x4 acc[4][4];
#pragma unroll
    for (int mt = 0; mt < 4; ++mt)
#pragma unroll
        for (int nt = 0; nt < 4; ++nt)
            acc[mt][nt] = (f32x4){0.f, 0.f, 0.f, 0.f};

    int r_m[4], c_m[4], rl[4];
#pragma unroll
    for (int mt = 0; mt < 4; ++mt) {
        int s = sbase + mt * 16 + lo;
        r_m[mt] = (s >> 5) & 31;
        c_m[mt] = s & 31;
        rl[mt] = s - sblk + 32;
    }

    auto load_b = [&](const unsigned short* wt, int ks, int nt) -> bf16x8 {
        const unsigned short* bp = wt + (nt * 16 + lo) * 64 + ks * 32 + quad * 8;
        return __builtin_bit_cast(bf16x8, *(const s16x8*)bp);
    };

    auto run_tap_lds = [&](int tap, int d, const bool ok[4]) {
        const unsigned short* wt = wq + tap * 4096;
#pragma unroll
        for (int ks = 0; ks < 2; ++ks) {
            bf16x8 bf[4];
#pragma unroll
            for (int nt = 0; nt < 4; ++nt) bf[nt] = load_b(wt, ks, nt);
            int j = ks * 4 + quad;
#pragma unroll
            for (int mt = 0; mt < 4; ++mt) {
                int row = rl[mt] + d;
                s16x8 raw = *((const s16x8*)alds + row * 8 + (j ^ (row & 7)));
                s16x8 zx = {0, 0, 0, 0, 0, 0, 0, 0};
                raw = ok[mt] ? raw : zx;
                bf16x8 af = __builtin_bit_cast(bf16x8, raw);
#pragma unroll
                for (int nt = 0; nt < 4; ++nt)
                    acc[mt][nt] = __builtin_amdgcn_mfma_f32_16x16x32_bf16(af, bf[nt], acc[mt][nt], 0, 0, 0);
            }
        }
    };

    auto run_tap_gather = [&](int tap, int d) {
        const unsigned short* wt = wq + tap * 4096;
#pragma unroll
        for (int ks = 0; ks < 2; ++ks) {
            bf16x8 bf[4];
#pragma unroll
            for (int nt = 0; nt < 4; ++nt) bf[nt] = load_b(wt, ks, nt);
            const float* gp = xb + (size_t)(ks * 32 + quad * 8) * SB + d;
#pragma unroll
            for (int mt = 0; mt < 4; ++mt) {
                const float* ap = gp + sbase + mt * 16 + lo;
                unsigned pk[4];
#pragma unroll
                for (int u = 0; u < 4; ++u)
                    pk[u] = pk2(ap[(size_t)(2 * u) * SB], ap[(size_t)(2 * u + 1) * SB]);
                uint4 v = make_uint4(pk[0], pk[1], pk[2], pk[3]);
                bf16x8 af = __builtin_bit_cast(bf16x8, v);
#pragma unroll
                for (int nt = 0; nt < 4; ++nt)
                    acc[mt][nt] = __builtin_amdgcn_mfma_f32_16x16x32_bf16(af, bf[nt], acc[mt][nt], 0, 0, 0);
            }
        }
    };

    {
        bool ok_all[4] = {true, true, true, true};
        run_tap_lds(0, 0, ok_all);
    }
    if (t > 0)  run_tap_gather(1, -1024);
    if (t < 31) run_tap_gather(2, 1024);
    {
        bool ok[4];
#pragma unroll
        for (int mt = 0; mt < 4; ++mt) ok[mt] = (r_m[mt] > 0);
        run_tap_lds(3, -32, ok);
#pragma unroll
        for (int mt = 0; mt < 4; ++mt) ok[mt] = (r_m[mt] < 31);
        run_tap_lds(4, 32, ok);
#pragma unroll
        for (int mt = 0; mt < 4; ++mt) ok[mt] = (c_m[mt] > 0);
        run_tap_lds(5, -1, ok);
#pragma unroll
        for (int mt = 0; mt < 4; ++mt) ok[mt] = (c_m[mt] < 31);
        run_tap_lds(6, 1, ok);
    }

#pragma unroll
    for (int mt = 0; mt < 4; ++mt) {
#pragma unroll
        for (int nt = 0; nt < 4; ++nt) {
            int o = nt * 16 + lo;
            size_t off = ((size_t)(b * COUT + o)) * SB + sbase + mt * 16 + quad * 4;
            *(f32x4*)(out + off) = acc[mt][nt];
        }
    }
}

// ---------------- tier-3 fallback: fp32 direct ----------------
__global__ void fallback_kernel(const float* __restrict__ x,
                                const float* __restrict__ w0, const float* __restrict__ w1,
                                const float* __restrict__ w2, const float* __restrict__ w3,
                                const float* __restrict__ w4, const float* __restrict__ w5,
                                const float* __restrict__ w6,
                                float* __restrict__ out) {
    int bid = blockIdx.x;
    int b = bid >> 11;
    int og = (bid >> 7) & 15;
    int sblk = (bid & 127) << 8;
    int tid = threadIdx.x;
    __shared__ float wl[7][4][64];
    const float* wp[7] = {w0, w1, w2, w3, w4, w5, w6};
    for (int k = tid; k < 7 * 4 * 64; k += 256) {
        int tap = k >> 8, oo = (k >> 6) & 3, i = k & 63;
        wl[tap][oo][i] = wp[tap][(og * 4 + oo) * 64 + i];
    }
    __syncthreads();
    int s = sblk + tid;
    int t = s >> 10, r = (s >> 5) & 31, c = s & 31;
    const float* xb = x + (size_t)b * CIN * SB + s;
    float a0 = 0, a1 = 0, a2 = 0, a3 = 0;
    for (int i = 0; i < 64; ++i) {
        const float* xi = xb + (size_t)i * SB;
        float vs = xi[0];
        float vtp = (t > 0) ? xi[-1024] : 0.f;
        float vtm = (t < 31) ? xi[1024] : 0.f;
        float vrp = (r > 0) ? xi[-32] : 0.f;
        float vrm = (r < 31) ? xi[32] : 0.f;
        float vcp = (c > 0) ? xi[-1] : 0.f;
        float vcm = (c < 31) ? xi[1] : 0.f;
        a0 += wl[0][0][i] * vs + wl[1][0][i] * vtp + wl[2][0][i] * vtm + wl[3][0][i] * vrp + wl[4][0][i] * vrm + wl[5][0][i] * vcp + wl[6][0][i] * vcm;
        a1 += wl[0][1][i] * vs + wl[1][1][i] * vtp + wl[2][1][i] * vtm + wl[3][1][i] * vrp + wl[4][1][i] * vrm + wl[5][1][i] * vcp + wl[6][1][i] * vcm;
        a2 += wl[0][2][i] * vs + wl[1][2][i] * vtp + wl[2][2][i] * vtm + wl[3][2][i] * vrp + wl[4][2][i] * vrm + wl[5][2][i] * vcp + wl[6][2][i] * vcm;
        a3 += wl[0][3][i] * vs + wl[1][3][i] * vtp + wl[2][3][i] * vtm + wl[3][3][i] * vrp + wl[4][3][i] * vrm + wl[5][3][i] * vcp + wl[6][3][i] * vcm;
    }
    size_t obase = ((size_t)b * COUT + og * 4) * SB + s;
    out[obase] = a0;
    out[obase + SB] = a1;
    out[obase + 2 * (size_t)SB] = a2;
    out[obase + 3 * (size_t)SB] = a3;
}

extern "C" void kernel_launch(void* const* d_in, const int* in_sizes, int n_in,
                              void* d_out, int out_size, void* d_ws, size_t ws_size,
                              hipStream_t stream) {
    const float* x = (const float*)d_in[0];
    const float* w0 = (const float*)d_in[1];
    const float* w1 = (const float*)d_in[2];
    const float* w2 = (const float*)d_in[3];
    const float* w3 = (const float*)d_in[4];
    const float* w4 = (const float*)d_in[5];
    const float* w5 = (const float*)d_in[6];
    const float* w6 = (const float*)d_in[7];
    float* out = (float*)d_out;

    size_t need_w = (size_t)7 * 4096 * 2;                        // 56 KB weights
    size_t need_full = need_w + (size_t)NB * CIN * SB * 2;       // + 32 MB bf16 x
    if (d_ws != nullptr && ws_size >= need_full) {
        unsigned short* wsp = (unsigned short*)d_ws;
        prep2_kernel<<<4103, 256, 0, stream>>>(x, w0, w1, w2, w3, w4, w5, w6, wsp);
        conv4_kernel<<<2048, 256, 0, stream>>>(wsp + 7 * 4096, wsp, out);
    } else if (d_ws != nullptr && ws_size >= need_w) {
        unsigned short* wsp = (unsigned short*)d_ws;
        wprep_kernel<<<7, 256, 0, stream>>>(w0, w1, w2, w3, w4, w5, w6, wsp);
        conv_kernel<<<1024, 256, 0, stream>>>(x, wsp, out);
    } else {
        fallback_kernel<<<8 * 16 * 128, 256, 0, stream>>>(x, w0, w1, w2, w3, w4, w5, w6, out);
    }
}

// Round 4
// 169.411 us; speedup vs baseline: 1.7826x; 1.2287x over previous
//
#include <hip/hip_runtime.h>

// DirectionalConv3d: B=8, C_IN=C_OUT=64, T=R=32, CO=32
// v5 design:
//  pass 1 (prep2): x fp32 [b][ch][s] -> bf16 [b][s][ch] in d_ws (+ bf16 weights).
//  pass 2 (conv5): latency-elimination version.
//    - center window (320 rows, 40KB) staged via async global_load_lds with
//      PRE-SWIZZLED SOURCE addresses (LDS dest linear, reads XOR-swizzled).
//    - t+-1 A-frags prefetched to VGPRs before the barrier, consumed first.
//    - LDS taps: 8x ds_read_b128 batched ahead of 32 MFMAs per tap.
//    - __launch_bounds__(256,2): allow 256 VGPR (no spill, no starvation).
// Tier 2 fallback: fused LDS kernel reading fp32 x (ws >= 56KB only).
// Tier 3 fallback: fp32 direct.

#define SB 32768   // spatial per batch (T*R*CO)
#define CIN 64
#define COUT 64
#define NB 8

typedef short s16x8 __attribute__((ext_vector_type(8)));
typedef __bf16 bf16x8 __attribute__((ext_vector_type(8)));
typedef float f32x4 __attribute__((ext_vector_type(4)));

__device__ __forceinline__ unsigned f2bf(float f) {
    unsigned u = __float_as_uint(f);
    u += 0x7FFFu + ((u >> 16) & 1u);   // round-to-nearest-even
    return u >> 16;
}
__device__ __forceinline__ unsigned pk2(float lo, float hi) {
    return f2bf(lo) | (f2bf(hi) << 16);
}

__device__ __forceinline__ void gload_lds16(const void* g, void* l) {
    __builtin_amdgcn_global_load_lds(
        (const __attribute__((address_space(1))) void*)g,
        (__attribute__((address_space(3))) void*)l, 16, 0, 0);
}

// ---------------- weight prep (tier-2 path): fp32 -> bf16, [tap][o][i] ----------------
__global__ __launch_bounds__(256) void wprep_kernel(const float* __restrict__ w0,
                            const float* __restrict__ w1, const float* __restrict__ w2,
                            const float* __restrict__ w3, const float* __restrict__ w4,
                            const float* __restrict__ w5, const float* __restrict__ w6,
                            unsigned short* __restrict__ ws) {
    int tap = blockIdx.x;
    int tid = threadIdx.x;
    const float* w = (tap == 0) ? w0 : (tap == 1) ? w1 : (tap == 2) ? w2
                   : (tap == 3) ? w3 : (tap == 4) ? w4 : (tap == 5) ? w5 : w6;
    unsigned p[8];
#pragma unroll
    for (int j = 0; j < 8; ++j)
        p[j] = pk2(w[tid * 16 + 2 * j], w[tid * 16 + 2 * j + 1]);
    uint4* dp = (uint4*)(ws + tap * 4096 + tid * 16);
    dp[0] = make_uint4(p[0], p[1], p[2], p[3]);
    dp[1] = make_uint4(p[4], p[5], p[6], p[7]);
}

// ---------------- pass 1: weights + x transpose/convert (LDS-free) ----------------
// grid 4103 = 4096 x-blocks + 7 weight taps. x-block: 256 thr, thread owns
// (b, s2, cg) producing rows s=2*s2, s+1 chunk cg (8 channels):
//   reads 8 x float2 along s (full 64B lines), writes 2 x uint4 (128B-contig).
// XCD chunking: batch b -> XCD b, so xq[b] lands hot in XCD b's L2 for conv5.
__global__ __launch_bounds__(256) void prep2_kernel(const float* __restrict__ x,
                            const float* __restrict__ w0, const float* __restrict__ w1,
                            const float* __restrict__ w2, const float* __restrict__ w3,
                            const float* __restrict__ w4, const float* __restrict__ w5,
                            const float* __restrict__ w6,
                            unsigned short* __restrict__ ws) {
    int bid = blockIdx.x;
    int tid = threadIdx.x;
    if (bid >= 4096) {                 // weight blocks
        int tap = bid - 4096;
        const float* w = (tap == 0) ? w0 : (tap == 1) ? w1 : (tap == 2) ? w2
                       : (tap == 3) ? w3 : (tap == 4) ? w4 : (tap == 5) ? w5 : w6;
        unsigned p[8];
#pragma unroll
        for (int j = 0; j < 8; ++j)
            p[j] = pk2(w[tid * 16 + 2 * j], w[tid * 16 + 2 * j + 1]);
        uint4* dp = (uint4*)(ws + tap * 4096 + tid * 16);
        dp[0] = make_uint4(p[0], p[1], p[2], p[3]);
        dp[1] = make_uint4(p[4], p[5], p[6], p[7]);
        return;
    }
    int lbid = ((bid & 7) << 9) | (bid >> 3);   // bijective: 4096 % 8 == 0
    int b = lbid >> 9;                          // batch = XCD
    int i = (lbid & 511) * 256 + tid;           // [0, 131072) per batch
    int cg = i & 7;                             // channel group (8 ch)
    int s = (i >> 3) * 2;                       // even spatial row
    const float* xb = x + (size_t)b * CIN * SB;
    unsigned short* xq = ws + 7 * 4096;
    unsigned pa[4], pb[4];
#pragma unroll
    for (int u = 0; u < 4; ++u) {
        int ch = cg * 8 + 2 * u;
        float2 v0 = *(const float2*)(xb + (size_t)ch * SB + s);
        float2 v1 = *(const float2*)(xb + (size_t)(ch + 1) * SB + s);
        pa[u] = pk2(v0.x, v1.x);
        pb[u] = pk2(v0.y, v1.y);
    }
    uint4* dst = (uint4*)(xq + ((size_t)b * SB + s) * 64 + cg * 8);
    dst[0] = make_uint4(pa[0], pa[1], pa[2], pa[3]);   // row s
    dst[8] = make_uint4(pb[0], pb[1], pb[2], pb[3]);   // row s+1 (+128B)
}

// ---------------- pass 2: async-staged MFMA conv ----------------
// grid 1024 = 8 b x 128 s-tiles of 256 (XCD-chunked: batch b pinned to XCD b).
// Block 256 thr = 4 waves; wave: 64 s x 64 o = acc[4][4], K=448 via
// mfma_f32_16x16x32_bf16.
__global__ __launch_bounds__(256, 2) void conv5_kernel(const unsigned short* __restrict__ xq,
                                                       const unsigned short* __restrict__ wq,
                                                       float* __restrict__ out) {
    __shared__ uint4 alds[2560];   // 40 KB, LINEAR dest (global_load_lds), swizzle in source
    int bid = blockIdx.x;
    int lbid = ((bid & 7) << 7) | (bid >> 3);   // bijective: 1024 % 8 == 0
    int b = lbid >> 7;
    int sblk = (lbid & 127) << 8;
    int tid = threadIdx.x;
    int lane = tid & 63;
    int wv = tid >> 6;                          // 0..3
    int lo = lane & 15;
    int quad = lane >> 4;
    int sbase = sblk + wv * 64;
    int t = sblk >> 10;                         // uniform within block
    // chunk index into bf16 [s][ch]: chunk = s*8 + ks*4 + quad (16B each)
    const uint4* xch = (const uint4*)(xq + (size_t)b * (CIN * SB));

    // ---- stage center window [sblk-32, sblk+288): 40 async 16B-DMA per wave=10 ----
    // LDS chunk (row, sc) holds global column sc ^ (row&7)  (source pre-swizzle);
    // readers use the same XOR -> conflict-free b128 reads (verified layout).
#pragma unroll
    for (int i = 0; i < 10; ++i) {
        int cid = wv * 640 + i * 64 + lane;     // 0..2559
        int row = cid >> 3;
        int sc = cid & 7;
        int grow = sblk - 32 + row;
        grow = grow < 0 ? 0 : (grow > SB - 1 ? SB - 1 : grow);  // clamped rows feed masked lanes only
        const uint4* g = xch + ((size_t)grow << 3) + (sc ^ (row & 7));
        gload_lds16((const void*)g, (void*)(alds + wv * 640 + i * 64));
    }

    int s_m[4], r_m[4], c_m[4], rl[4];
#pragma unroll
    for (int mt = 0; mt < 4; ++mt) {
        int s = sbase + mt * 16 + lo;           // A row: m = lane&15
        s_m[mt] = s;
        r_m[mt] = (s >> 5) & 31;
        c_m[mt] = s & 31;
        rl[mt] = s - sblk + 32;                 // LDS local row
    }

    // ---- t+-1 A-frag prefetch (block-uniform validity), consumed right after barrier ----
    bool htm = (t > 0), htp = (t < 31);
    uint4 tgm[8], tgp[8];
    if (htm) {
#pragma unroll
        for (int ks = 0; ks < 2; ++ks)
#pragma unroll
            for (int mt = 0; mt < 4; ++mt)
                tgm[ks * 4 + mt] = xch[(size_t)(s_m[mt] - 1024) * 8 + ks * 4 + quad];
    }
    if (htp) {
#pragma unroll
        for (int ks = 0; ks < 2; ++ks)
#pragma unroll
            for (int mt = 0; mt < 4; ++mt)
                tgp[ks * 4 + mt] = xch[(size_t)(s_m[mt] + 1024) * 8 + ks * 4 + quad];
    }

    __syncthreads();   // drains vmcnt(0): staging AND prefetch complete

    f32x4 acc[4][4];
#pragma unroll
    for (int mt = 0; mt < 4; ++mt)
#pragma unroll
        for (int nt = 0; nt < 4; ++nt)
            acc[mt][nt] = (f32x4){0.f, 0.f, 0.f, 0.f};

    const s16x8 zz = {0, 0, 0, 0, 0, 0, 0, 0};

    auto load_b = [&](const unsigned short* wt, int ks, int nt) -> bf16x8 {
        const unsigned short* bp = wt + (nt * 16 + lo) * 64 + ks * 32 + quad * 8;
        return __builtin_bit_cast(bf16x8, *(const s16x8*)bp);
    };

    // t-taps from prefetched regs (short live range; all MFMAs ready instantly)
    auto run_tap_reg = [&](int tap, const uint4 (&tg)[8]) {
        const unsigned short* wt = wq + tap * 4096;
        bf16x8 bf[2][4];
#pragma unroll
        for (int ks = 0; ks < 2; ++ks)
#pragma unroll
            for (int nt = 0; nt < 4; ++nt) bf[ks][nt] = load_b(wt, ks, nt);
#pragma unroll
        for (int ks = 0; ks < 2; ++ks)
#pragma unroll
            for (int mt = 0; mt < 4; ++mt) {
                bf16x8 af = __builtin_bit_cast(bf16x8, tg[ks * 4 + mt]);
#pragma unroll
                for (int nt = 0; nt < 4; ++nt)
                    acc[mt][nt] = __builtin_amdgcn_mfma_f32_16x16x32_bf16(af, bf[ks][nt], acc[mt][nt], 0, 0, 0);
            }
    };

    // near taps: batch all 8 ds_read_b128 ahead of the 32 MFMAs
    auto run_tap_lds = [&](int tap, int d, const bool (&ok)[4]) {
        const unsigned short* wt = wq + tap * 4096;
        bf16x8 bf[2][4];
#pragma unroll
        for (int ks = 0; ks < 2; ++ks)
#pragma unroll
            for (int nt = 0; nt < 4; ++nt) bf[ks][nt] = load_b(wt, ks, nt);
        s16x8 a[2][4];
#pragma unroll
        for (int ks = 0; ks < 2; ++ks)
#pragma unroll
            for (int mt = 0; mt < 4; ++mt) {
                int row = rl[mt] + d;            // always in [0,320)
                a[ks][mt] = *((const s16x8*)alds + row * 8 + ((ks * 4 + quad) ^ (row & 7)));
            }
#pragma unroll
        for (int ks = 0; ks < 2; ++ks)
#pragma unroll
            for (int mt = 0; mt < 4; ++mt) {
                s16x8 raw = ok[mt] ? a[ks][mt] : zz;
                bf16x8 af = __builtin_bit_cast(bf16x8, raw);
#pragma unroll
                for (int nt = 0; nt < 4; ++nt)
                    acc[mt][nt] = __builtin_amdgcn_mfma_f32_16x16x32_bf16(af, bf[ks][nt], acc[mt][nt], 0, 0, 0);
            }
    };

    if (htm) run_tap_reg(1, tgm);               // t-1  (frees tgm regs early)
    if (htp) run_tap_reg(2, tgp);               // t+1
    {
        bool ok_all[4] = {true, true, true, true};
        run_tap_lds(0, 0, ok_all);              // self
    }
    {
        bool ok[4];
#pragma unroll
        for (int mt = 0; mt < 4; ++mt) ok[mt] = (r_m[mt] > 0);
        run_tap_lds(3, -32, ok);                // r-1
#pragma unroll
        for (int mt = 0; mt < 4; ++mt) ok[mt] = (r_m[mt] < 31);
        run_tap_lds(4, 32, ok);                 // r+1
#pragma unroll
        for (int mt = 0; mt < 4; ++mt) ok[mt] = (c_m[mt] > 0);
        run_tap_lds(5, -1, ok);                 // c-1
#pragma unroll
        for (int mt = 0; mt < 4; ++mt) ok[mt] = (c_m[mt] < 31);
        run_tap_lds(6, 1, ok);                  // c+1
    }

    // D layout: col(n=o) = lane&15, row(m=s) = quad*4 + reg -> full 64B lines per wave
#pragma unroll
    for (int mt = 0; mt < 4; ++mt) {
#pragma unroll
        for (int nt = 0; nt < 4; ++nt) {
            int o = nt * 16 + lo;
            size_t off = ((size_t)(b * COUT + o)) * SB + sbase + mt * 16 + quad * 4;
            *(f32x4*)(out + off) = acc[mt][nt];
        }
    }
}

// ---------------- tier-2 fallback: fused LDS kernel on fp32 x ----------------
__global__ __launch_bounds__(256) void conv_kernel(const float* __restrict__ x,
                                                   const unsigned short* __restrict__ wq,
                                                   float* __restrict__ out) {
    __shared__ uint4 alds[2560];
    int bid = blockIdx.x;
    int b = bid >> 7;
    int sblk = (bid & 127) << 8;
    int tid = threadIdx.x;
    const float* xb = x + (size_t)b * CIN * SB;

    {
        int rl = 32 + tid;
        const float* xp = xb + sblk + tid;
#pragma unroll
        for (int c = 0; c < 4; ++c) {
            unsigned pk[8];
#pragma unroll
            for (int u = 0; u < 8; ++u)
                pk[u] = pk2(xp[(size_t)(c * 16 + 2 * u) * SB],
                            xp[(size_t)(c * 16 + 2 * u + 1) * SB]);
            alds[rl * 8 + ((2 * c) ^ (rl & 7))] = make_uint4(pk[0], pk[1], pk[2], pk[3]);
            alds[rl * 8 + ((2 * c + 1) ^ (rl & 7))] = make_uint4(pk[4], pk[5], pk[6], pk[7]);
        }
    }
    {
        int hrow = tid & 63;
        int rl = (hrow < 32) ? hrow : hrow + 256;
        int s = sblk - 32 + rl;
        s = max(0, min(SB - 1, s));
        int ic = tid >> 6;
        const float* xp = xb + s + (size_t)(ic * 16) * SB;
        unsigned pk[8];
#pragma unroll
        for (int u = 0; u < 8; ++u)
            pk[u] = pk2(xp[(size_t)(2 * u) * SB], xp[(size_t)(2 * u + 1) * SB]);
        alds[rl * 8 + ((2 * ic) ^ (rl & 7))] = make_uint4(pk[0], pk[1], pk[2], pk[3]);
        alds[rl * 8 + ((2 * ic + 1) ^ (rl & 7))] = make_uint4(pk[4], pk[5], pk[6], pk[7]);
    }
    __syncthreads();

    int lane = tid & 63;
    int wv = tid >> 6;
    int lo = lane & 15;
    int quad = lane >> 4;
    int sbase = sblk + wv * 64;
    int t = sblk >> 10;

    f32x4 acc[4][4];
#pragma unroll
    for (int mt = 0; mt < 4; ++mt)
#pragma unroll
        for (int nt = 0; nt < 4; ++nt)
            acc[mt][nt] = (f32x4){0.f, 0.f, 0.f, 0.f};

    int r_m[4], c_m[4], rl[4];
#pragma unroll
    for (int mt = 0; mt < 4; ++mt) {
        int s = sbase + mt * 16 + lo;
        r_m[mt] = (s >> 5) & 31;
        c_m[mt] = s & 31;
        rl[mt] = s - sblk + 32;
    }

    auto load_b = [&](const unsigned short* wt, int ks, int nt) -> bf16x8 {
        const unsigned short* bp = wt + (nt * 16 + lo) * 64 + ks * 32 + quad * 8;
        return __builtin_bit_cast(bf16x8, *(const s16x8*)bp);
    };

    auto run_tap_lds = [&](int tap, int d, const bool ok[4]) {
        const unsigned short* wt = wq + tap * 4096;
#pragma unroll
        for (int ks = 0; ks < 2; ++ks) {
            bf16x8 bf[4];
#pragma unroll
            for (int nt = 0; nt < 4; ++nt) bf[nt] = load_b(wt, ks, nt);
            int j = ks * 4 + quad;
#pragma unroll
            for (int mt = 0; mt < 4; ++mt) {
                int row = rl[mt] + d;
                s16x8 raw = *((const s16x8*)alds + row * 8 + (j ^ (row & 7)));
                s16x8 zx = {0, 0, 0, 0, 0, 0, 0, 0};
                raw = ok[mt] ? raw : zx;
                bf16x8 af = __builtin_bit_cast(bf16x8, raw);
#pragma unroll
                for (int nt = 0; nt < 4; ++nt)
                    acc[mt][nt] = __builtin_amdgcn_mfma_f32_16x16x32_bf16(af, bf[nt], acc[mt][nt], 0, 0, 0);
            }
        }
    };

    auto run_tap_gather = [&](int tap, int d) {
        const unsigned short* wt = wq + tap * 4096;
#pragma unroll
        for (int ks = 0; ks < 2; ++ks) {
            bf16x8 bf[4];
#pragma unroll
            for (int nt = 0; nt < 4; ++nt) bf[nt] = load_b(wt, ks, nt);
            const float* gp = xb + (size_t)(ks * 32 + quad * 8) * SB + d;
#pragma unroll
            for (int mt = 0; mt < 4; ++mt) {
                const float* ap = gp + sbase + mt * 16 + lo;
                unsigned pk[4];
#pragma unroll
                for (int u = 0; u < 4; ++u)
                    pk[u] = pk2(ap[(size_t)(2 * u) * SB], ap[(size_t)(2 * u + 1) * SB]);
                uint4 v = make_uint4(pk[0], pk[1], pk[2], pk[3]);
                bf16x8 af = __builtin_bit_cast(bf16x8, v);
#pragma unroll
                for (int nt = 0; nt < 4; ++nt)
                    acc[mt][nt] = __builtin_amdgcn_mfma_f32_16x16x32_bf16(af, bf[nt], acc[mt][nt], 0, 0, 0);
            }
        }
    };

    {
        bool ok_all[4] = {true, true, true, true};
        run_tap_lds(0, 0, ok_all);
    }
    if (t > 0)  run_tap_gather(1, -1024);
    if (t < 31) run_tap_gather(2, 1024);
    {
        bool ok[4];
#pragma unroll
        for (int mt = 0; mt < 4; ++mt) ok[mt] = (r_m[mt] > 0);
        run_tap_lds(3, -32, ok);
#pragma unroll
        for (int mt = 0; mt < 4; ++mt) ok[mt] = (r_m[mt] < 31);
        run_tap_lds(4, 32, ok);
#pragma unroll
        for (int mt = 0; mt < 4; ++mt) ok[mt] = (c_m[mt] > 0);
        run_tap_lds(5, -1, ok);
#pragma unroll
        for (int mt = 0; mt < 4; ++mt) ok[mt] = (c_m[mt] < 31);
        run_tap_lds(6, 1, ok);
    }

#pragma unroll
    for (int mt = 0; mt < 4; ++mt) {
#pragma unroll
        for (int nt = 0; nt < 4; ++nt) {
            int o = nt * 16 + lo;
            size_t off = ((size_t)(b * COUT + o)) * SB + sbase + mt * 16 + quad * 4;
            *(f32x4*)(out + off) = acc[mt][nt];
        }
    }
}

// ---------------- tier-3 fallback: fp32 direct ----------------
__global__ void fallback_kernel(const float* __restrict__ x,
                                const float* __restrict__ w0, const float* __restrict__ w1,
                                const float* __restrict__ w2, const float* __restrict__ w3,
                                const float* __restrict__ w4, const float* __restrict__ w5,
                                const float* __restrict__ w6,
                                float* __restrict__ out) {
    int bid = blockIdx.x;
    int b = bid >> 11;
    int og = (bid >> 7) & 15;
    int sblk = (bid & 127) << 8;
    int tid = threadIdx.x;
    __shared__ float wl[7][4][64];
    const float* wp[7] = {w0, w1, w2, w3, w4, w5, w6};
    for (int k = tid; k < 7 * 4 * 64; k += 256) {
        int tap = k >> 8, oo = (k >> 6) & 3, i = k & 63;
        wl[tap][oo][i] = wp[tap][(og * 4 + oo) * 64 + i];
    }
    __syncthreads();
    int s = sblk + tid;
    int t = s >> 10, r = (s >> 5) & 31, c = s & 31;
    const float* xb = x + (size_t)b * CIN * SB + s;
    float a0 = 0, a1 = 0, a2 = 0, a3 = 0;
    for (int i = 0; i < 64; ++i) {
        const float* xi = xb + (size_t)i * SB;
        float vs = xi[0];
        float vtp = (t > 0) ? xi[-1024] : 0.f;
        float vtm = (t < 31) ? xi[1024] : 0.f;
        float vrp = (r > 0) ? xi[-32] : 0.f;
        float vrm = (r < 31) ? xi[32] : 0.f;
        float vcp = (c > 0) ? xi[-1] : 0.f;
        float vcm = (c < 31) ? xi[1] : 0.f;
        a0 += wl[0][0][i] * vs + wl[1][0][i] * vtp + wl[2][0][i] * vtm + wl[3][0][i] * vrp + wl[4][0][i] * vrm + wl[5][0][i] * vcp + wl[6][0][i] * vcm;
        a1 += wl[0][1][i] * vs + wl[1][1][i] * vtp + wl[2][1][i] * vtm + wl[3][1][i] * vrp + wl[4][1][i] * vrm + wl[5][1][i] * vcp + wl[6][1][i] * vcm;
        a2 += wl[0][2][i] * vs + wl[1][2][i] * vtp + wl[2][2][i] * vtm + wl[3][2][i] * vrp + wl[4][2][i] * vrm + wl[5][2][i] * vcp + wl[6][2][i] * vcm;
        a3 += wl[0][3][i] * vs + wl[1][3][i] * vtp + wl[2][3][i] * vtm + wl[3][3][i] * vrp + wl[4][3][i] * vrm + wl[5][3][i] * vcp + wl[6][3][i] * vcm;
    }
    size_t obase = ((size_t)b * COUT + og * 4) * SB + s;
    out[obase] = a0;
    out[obase + SB] = a1;
    out[obase + 2 * (size_t)SB] = a2;
    out[obase + 3 * (size_t)SB] = a3;
}

extern "C" void kernel_launch(void* const* d_in, const int* in_sizes, int n_in,
                              void* d_out, int out_size, void* d_ws, size_t ws_size,
                              hipStream_t stream) {
    const float* x = (const float*)d_in[0];
    const float* w0 = (const float*)d_in[1];
    const float* w1 = (const float*)d_in[2];
    const float* w2 = (const float*)d_in[3];
    const float* w3 = (const float*)d_in[4];
    const float* w4 = (const float*)d_in[5];
    const float* w5 = (const float*)d_in[6];
    const float* w6 = (const float*)d_in[7];
    float* out = (float*)d_out;

    size_t need_w = (size_t)7 * 4096 * 2;                        // 56 KB weights
    size_t need_full = need_w + (size_t)NB * CIN * SB * 2;       // + 32 MB bf16 x
    if (d_ws != nullptr && ws_size >= need_full) {
        unsigned short* wsp = (unsigned short*)d_ws;
        prep2_kernel<<<4103, 256, 0, stream>>>(x, w0, w1, w2, w3, w4, w5, w6, wsp);
        conv5_kernel<<<1024, 256, 0, stream>>>(wsp + 7 * 4096, wsp, out);
    } else if (d_ws != nullptr && ws_size >= need_w) {
        unsigned short* wsp = (unsigned short*)d_ws;
        wprep_kernel<<<7, 256, 0, stream>>>(w0, w1, w2, w3, w4, w5, w6, wsp);
        conv_kernel<<<1024, 256, 0, stream>>>(x, wsp, out);
    } else {
        fallback_kernel<<<8 * 16 * 128, 256, 0, stream>>>(x, w0, w1, w2, w3, w4, w5, w6, out);
    }
}